// Round 1
// baseline (1268.914 us; speedup 1.0000x reference)
//
#include <hip/hip_runtime.h>

#define N_NODES 131072
#define E_EDGES 524288
#define B_GR    2048
#define H_DIM   128
#define NF_DIM  30
#define GF_DIM  4415
#define BN_SCALE 0.9999950000374997f   // 1/sqrt(1+1e-5)

// ---------------- graph prep ----------------

__global__ void k_zero_int(int* __restrict__ p, int n){
    int i = blockIdx.x*256 + threadIdx.x;
    if(i < n) p[i] = 0;
}

__global__ void k_count(const int* __restrict__ dst, int* __restrict__ counts){
    int e = blockIdx.x*256 + threadIdx.x;
    if(e < E_EDGES) atomicAdd(&counts[dst[e]], 1);
}

__global__ void k_scan1(int* __restrict__ counts, int* __restrict__ bsums){
    __shared__ int s[1024];
    int t = threadIdx.x;
    int gi = blockIdx.x*1024 + t;
    int v = counts[gi];
    s[t] = v; __syncthreads();
    for(int off=1; off<1024; off<<=1){
        int x = (t>=off) ? s[t-off] : 0;
        __syncthreads();
        s[t] += x;
        __syncthreads();
    }
    counts[gi] = s[t] - v;              // exclusive within block
    if(t == 1023) bsums[blockIdx.x] = s[t];
}

__global__ void k_scan2(int* __restrict__ bsums){
    __shared__ int s[128];
    int t = threadIdx.x;
    int v = bsums[t]; s[t] = v; __syncthreads();
    for(int off=1; off<128; off<<=1){
        int x = (t>=off) ? s[t-off] : 0;
        __syncthreads();
        s[t] += x;
        __syncthreads();
    }
    bsums[t] = s[t] - v;                // exclusive block offsets
}

__global__ void k_scan3(const int* __restrict__ counts, const int* __restrict__ bsums,
                        int* __restrict__ rowptr){
    int i = blockIdx.x*1024 + threadIdx.x;
    rowptr[i] = counts[i] + bsums[blockIdx.x];
    if(i == 0) rowptr[N_NODES] = E_EDGES;
}

__global__ void k_dinv_cursor(const int* __restrict__ rowptr, float* __restrict__ dinv,
                              int* __restrict__ cursor){
    int n = blockIdx.x*256 + threadIdx.x;
    if(n < N_NODES){
        int a = rowptr[n], b = rowptr[n+1];
        dinv[n] = rsqrtf((float)(b - a) + 1.0f);   // deg = in-degree + self-loop
        cursor[n] = a;
    }
}

__global__ void k_fill(const int* __restrict__ src, const int* __restrict__ dst,
                       int* __restrict__ cursor, int* __restrict__ csr){
    int e = blockIdx.x*256 + threadIdx.x;
    if(e < E_EDGES){
        int p = atomicAdd(&cursor[dst[e]], 1);
        csr[p] = src[e];
    }
}

// ---------------- node embedding ----------------

__global__ void k_emb(const float* __restrict__ x, const float* __restrict__ W,
                      const float* __restrict__ b, float* __restrict__ h){
    int idx = blockIdx.x*256 + threadIdx.x;     // over N*128
    int n = idx >> 7, c = idx & 127;
    const float* xr = x + n*NF_DIM;
    float acc = b[c];
    #pragma unroll
    for(int k=0;k<NF_DIM;k++) acc = fmaf(xr[k], W[k*H_DIM + c], acc);
    h[idx] = fmaxf(acc, 0.f);
}

// ---------------- h @ Wg  (131072 x 128 x 128) ----------------

__global__ __launch_bounds__(256,2)
void k_matmul128(const float* __restrict__ A, const float* __restrict__ W,
                 float* __restrict__ C){
    __shared__ float sW[128*128];   // 64 KB
    __shared__ float sA[32*128];    // 16 KB
    for(int i=threadIdx.x;i<128*128;i+=256) sW[i] = W[i];
    int rg  = threadIdx.x >> 5;        // 0..7 -> rows rg*4..rg*4+3
    int cg4 = (threadIdx.x & 31)*4;    // cols cg4..cg4+3
    const int tiles = N_NODES/32;      // 4096
    for(int tile = blockIdx.x; tile < tiles; tile += gridDim.x){
        int rowBase = tile*32;
        __syncthreads();
        const float4* A4 = (const float4*)(A + rowBase*128);
        float4* sA4 = (float4*)sA;
        #pragma unroll
        for(int i=0;i<4;i++) sA4[threadIdx.x + 256*i] = A4[threadIdx.x + 256*i];
        __syncthreads();
        float4 acc0={0,0,0,0}, acc1={0,0,0,0}, acc2={0,0,0,0}, acc3={0,0,0,0};
        const float* a0 = sA + (rg*4+0)*128;
        const float* a1 = sA + (rg*4+1)*128;
        const float* a2 = sA + (rg*4+2)*128;
        const float* a3 = sA + (rg*4+3)*128;
        #pragma unroll 4
        for(int k=0;k<128;k++){
            float4 w = *(const float4*)(sW + k*128 + cg4);
            float A0=a0[k], A1=a1[k], A2=a2[k], A3=a3[k];
            acc0.x=fmaf(A0,w.x,acc0.x); acc0.y=fmaf(A0,w.y,acc0.y); acc0.z=fmaf(A0,w.z,acc0.z); acc0.w=fmaf(A0,w.w,acc0.w);
            acc1.x=fmaf(A1,w.x,acc1.x); acc1.y=fmaf(A1,w.y,acc1.y); acc1.z=fmaf(A1,w.z,acc1.z); acc1.w=fmaf(A1,w.w,acc1.w);
            acc2.x=fmaf(A2,w.x,acc2.x); acc2.y=fmaf(A2,w.y,acc2.y); acc2.z=fmaf(A2,w.z,acc2.z); acc2.w=fmaf(A2,w.w,acc2.w);
            acc3.x=fmaf(A3,w.x,acc3.x); acc3.y=fmaf(A3,w.y,acc3.y); acc3.z=fmaf(A3,w.z,acc3.z); acc3.w=fmaf(A3,w.w,acc3.w);
        }
        *(float4*)(C + (rowBase+rg*4+0)*128 + cg4) = acc0;
        *(float4*)(C + (rowBase+rg*4+1)*128 + cg4) = acc1;
        *(float4*)(C + (rowBase+rg*4+2)*128 + cg4) = acc2;
        *(float4*)(C + (rowBase+rg*4+3)*128 + cg4) = acc3;
    }
}

// ---------------- GCN aggregate + bias + BN + ReLU + residual ----------------

__global__ void k_aggregate(const float* __restrict__ hw, const float* __restrict__ dinv,
                            const int* __restrict__ rowptr, const int* __restrict__ csr,
                            const float* __restrict__ bias, const float* __restrict__ gamma,
                            const float* __restrict__ beta, float* __restrict__ h,
                            int residual){
    int wave = threadIdx.x >> 6, lane = threadIdx.x & 63;
    int n = blockIdx.x*4 + wave;
    int c = lane*2;
    float dn = dinv[n];
    const float2* hw2 = (const float2*)hw;
    float2 self = hw2[n*64 + lane];
    float ax = self.x*dn, ay = self.y*dn;
    int j0 = rowptr[n], j1 = rowptr[n+1];
    for(int j=j0;j<j1;j++){
        int s = csr[j];
        float ds = dinv[s];
        float2 v = hw2[s*64 + lane];
        ax = fmaf(v.x, ds, ax);
        ay = fmaf(v.y, ds, ay);
    }
    float v0 = fmaf(ax, dn, bias[c]);
    float v1 = fmaf(ay, dn, bias[c+1]);
    v0 = fmaf(v0, gamma[c]*BN_SCALE,   beta[c]);
    v1 = fmaf(v1, gamma[c+1]*BN_SCALE, beta[c+1]);
    v0 = fmaxf(v0, 0.f); v1 = fmaxf(v1, 0.f);
    float2* h2 = (float2*)h;
    if(residual){ float2 old = h2[n*64+lane]; v0 += old.x; v1 += old.y; }
    h2[n*64+lane] = make_float2(v0, v1);
}

// ---------------- pooling (64 contiguous nodes per graph) ----------------

__global__ void k_pool(const float* __restrict__ h, float* __restrict__ pool){
    int g = blockIdx.x, c = threadIdx.x;   // 128 threads
    const float* base = h + g*64*128;
    float s = 0.f, m = -3.4e38f;
    for(int i=0;i<64;i++){
        float v = base[i*128 + c];
        s += v; m = fmaxf(m, v);
    }
    pool[g*256 + c]       = s * (1.f/64.f);
    pool[g*256 + 128 + c] = m;
}

// ---------------- gene GEMM (2048 x 4415 x 256), split-K with atomics ----------------

__global__ void k_ginit(const float* __restrict__ bias, float* __restrict__ out){
    int i = blockIdx.x*256 + threadIdx.x;   // over B*256
    out[i] = bias[i & 255];
}

#define KC 552
__global__ __launch_bounds__(256)
void k_gemm_gf(const float* __restrict__ A, const float* __restrict__ W,
               float* __restrict__ out){
    __shared__ float sA[32*64];
    int rt = blockIdx.x & 63;
    int kc = blockIdx.x >> 6;
    int rowBase = rt*32;
    int kBase = kc*KC;
    int kEnd = kBase + KC; if(kEnd > GF_DIM) kEnd = GF_DIM;
    int c = threadIdx.x;
    float acc[32];
    #pragma unroll
    for(int r=0;r<32;r++) acc[r] = 0.f;
    for(int kk=kBase; kk<kEnd; kk+=64){
        int kw = kEnd - kk; if(kw > 64) kw = 64;
        __syncthreads();
        for(int idx=threadIdx.x; idx<32*64; idx+=256){
            int r = idx>>6, k2 = idx&63;
            sA[idx] = (k2 < kw) ? A[(rowBase+r)*GF_DIM + kk + k2] : 0.f;
        }
        __syncthreads();
        if(kw == 64){
            for(int k2=0;k2<64;k2++){
                float w = W[(kk+k2)*256 + c];
                #pragma unroll
                for(int r=0;r<32;r++) acc[r] = fmaf(sA[(r<<6)+k2], w, acc[r]);
            }
        } else {
            for(int k2=0;k2<kw;k2++){
                float w = W[(kk+k2)*256 + c];
                #pragma unroll
                for(int r=0;r<32;r++) acc[r] = fmaf(sA[(r<<6)+k2], w, acc[r]);
            }
        }
    }
    for(int r=0;r<32;r++) atomicAdd(&out[(rowBase+r)*256 + c], acc[r]);
}

__global__ void k_bnrelu256(float* __restrict__ g1, const float* __restrict__ gamma,
                            const float* __restrict__ beta){
    int i = blockIdx.x*256 + threadIdx.x;   // over B*256
    int c = i & 255;
    float v = fmaf(g1[i], gamma[c]*BN_SCALE, beta[c]);
    g1[i] = fmaxf(v, 0.f);
}

// ---------------- generic small dense:  out = act(A[2048,K] @ W[K,NC] + b) ----------------
// blockDim.x == NC, 16 rows per block; K, NC powers of two.

__global__ void k_dense(const float* __restrict__ A, int ldA, const float* __restrict__ W,
                        const float* __restrict__ bias, const float* __restrict__ gamma,
                        const float* __restrict__ beta, float* __restrict__ out, int ldOut,
                        int K, int logK, int NC, int relu){
    extern __shared__ float sA[];   // 16*K floats
    int rowBase = blockIdx.x*16;
    int c = threadIdx.x;
    for(int idx=threadIdx.x; idx<16*K; idx+=NC){
        int r = idx >> logK, k = idx & (K-1);
        sA[idx] = A[(rowBase+r)*ldA + k];
    }
    __syncthreads();
    float acc[16];
    float bb = bias[c];
    #pragma unroll
    for(int r=0;r<16;r++) acc[r] = bb;
    for(int k=0;k<K;k++){
        float w = W[k*NC + c];
        #pragma unroll
        for(int r=0;r<16;r++) acc[r] = fmaf(sA[(r<<logK)+k], w, acc[r]);
    }
    float gsc = 1.f, bsh = 0.f;
    if(gamma){ gsc = gamma[c]*BN_SCALE; bsh = beta[c]; }
    #pragma unroll
    for(int r=0;r<16;r++){
        float v = acc[r];
        if(gamma) v = fmaf(v, gsc, bsh);
        if(relu)  v = fmaxf(v, 0.f);
        out[(rowBase+r)*ldOut + c] = v;
    }
}

// ---------------- final [2048,64] @ [64,1] ----------------

__global__ void k_final(const float* __restrict__ z2, const float* __restrict__ Wh3,
                        const float* __restrict__ bh3, float* __restrict__ out){
    int r = blockIdx.x*256 + threadIdx.x;
    if(r < B_GR){
        float acc = bh3[0];
        #pragma unroll
        for(int k=0;k<64;k++) acc = fmaf(z2[r*64+k], Wh3[k], acc);
        out[r] = acc;
    }
}

// ---------------- launch ----------------

extern "C" void kernel_launch(void* const* d_in, const int* in_sizes, int n_in,
                              void* d_out, int out_size, void* d_ws, size_t ws_size,
                              hipStream_t stream){
    (void)in_sizes; (void)n_in; (void)out_size; (void)ws_size;
    const float* x    = (const float*)d_in[0];
    const float* gf   = (const float*)d_in[1];
    const int*   ei   = (const int*)  d_in[2];
    const float* W_emb= (const float*)d_in[4];
    const float* b_emb= (const float*)d_in[5];
    const float* Wg   = (const float*)d_in[6];
    const float* bg   = (const float*)d_in[7];
    const float* bn_g = (const float*)d_in[8];
    const float* bn_b = (const float*)d_in[9];
    const float* Wd1  = (const float*)d_in[10];
    const float* bd1  = (const float*)d_in[11];
    const float* Wd2  = (const float*)d_in[12];
    const float* bd2  = (const float*)d_in[13];
    const float* Wge1 = (const float*)d_in[14];
    const float* bge1 = (const float*)d_in[15];
    const float* g_g  = (const float*)d_in[16];
    const float* g_b  = (const float*)d_in[17];
    const float* Wge2 = (const float*)d_in[18];
    const float* bge2 = (const float*)d_in[19];
    const float* Wh1  = (const float*)d_in[20];
    const float* bh1  = (const float*)d_in[21];
    const float* h_g  = (const float*)d_in[22];
    const float* h_b  = (const float*)d_in[23];
    const float* Wh2  = (const float*)d_in[24];
    const float* bh2  = (const float*)d_in[25];
    const float* Wh3  = (const float*)d_in[26];
    const float* bh3  = (const float*)d_in[27];
    float* outp = (float*)d_out;

    float* ws   = (float*)d_ws;
    float* h    = ws;
    float* hw   = h    + (size_t)N_NODES*H_DIM;
    float* dinv = hw   + (size_t)N_NODES*H_DIM;
    float* pool = dinv + N_NODES;
    float* g1   = pool + B_GR*256;
    float* t1   = g1   + B_GR*256;
    float* comb = t1   + B_GR*128;
    float* z    = comb + B_GR*256;
    float* z2   = z    + B_GR*128;
    int* rowptr = (int*)(z2 + B_GR*64);
    int* cursor = rowptr + (N_NODES+1);
    int* csr    = cursor + N_NODES;
    int* bsums  = csr + E_EDGES;

    const int* src = ei;
    const int* dst = ei + E_EDGES;

    // graph prep
    k_zero_int   <<<N_NODES/256, 256, 0, stream>>>(cursor, N_NODES);
    k_count      <<<E_EDGES/256, 256, 0, stream>>>(dst, cursor);
    k_scan1      <<<128, 1024, 0, stream>>>(cursor, bsums);
    k_scan2      <<<1, 128, 0, stream>>>(bsums);
    k_scan3      <<<128, 1024, 0, stream>>>(cursor, bsums, rowptr);
    k_dinv_cursor<<<N_NODES/256, 256, 0, stream>>>(rowptr, dinv, cursor);
    k_fill       <<<E_EDGES/256, 256, 0, stream>>>(src, dst, cursor, csr);

    // embedding
    k_emb<<<(N_NODES*H_DIM)/256, 256, 0, stream>>>(x, W_emb, b_emb, h);

    // 3 GCN layers
    for(int i=0;i<3;i++){
        k_matmul128<<<512, 256, 0, stream>>>(h, Wg + i*H_DIM*H_DIM, hw);
        k_aggregate<<<N_NODES/4, 256, 0, stream>>>(hw, dinv, rowptr, csr,
                                                   bg + i*H_DIM, bn_g + i*H_DIM,
                                                   bn_b + i*H_DIM, h, i > 0);
    }

    // pooling
    k_pool<<<B_GR, 128, 0, stream>>>(h, pool);

    // gene branch big GEMM
    k_ginit  <<<(B_GR*256)/256, 256, 0, stream>>>(bge1, g1);
    k_gemm_gf<<<64*8, 256, 0, stream>>>(gf, Wge1, g1);
    k_bnrelu256<<<(B_GR*256)/256, 256, 0, stream>>>(g1, g_g, g_b);

    // dense heads
    k_dense<<<B_GR/16, 128, 16*256*4, stream>>>(pool, 256, Wd1, bd1, nullptr, nullptr, t1,   128, 256, 8, 128, 1);
    k_dense<<<B_GR/16, 128, 16*128*4, stream>>>(t1,   128, Wd2, bd2, nullptr, nullptr, comb, 256, 128, 7, 128, 0);
    k_dense<<<B_GR/16, 128, 16*256*4, stream>>>(g1,   256, Wge2, bge2, nullptr, nullptr, comb+128, 256, 256, 8, 128, 1);
    k_dense<<<B_GR/16, 128, 16*256*4, stream>>>(comb, 256, Wh1, bh1, h_g, h_b, z, 128, 256, 8, 128, 1);
    k_dense<<<B_GR/16, 64,  16*128*4, stream>>>(z,    128, Wh2, bh2, nullptr, nullptr, z2, 64, 128, 7, 64, 1);
    k_final<<<B_GR/256, 256, 0, stream>>>(z2, Wh3, bh3, outp);
}

// Round 2
// 968.465 us; speedup vs baseline: 1.3102x; 1.3102x over previous
//
#include <hip/hip_runtime.h>

#define N_NODES 131072
#define E_EDGES 524288
#define B_GR    2048
#define H_DIM   128
#define NF_DIM  30
#define GF_DIM  4415
#define GF_PAD  4416            // 138*32
#define BN_SCALE 0.9999950000374997f   // 1/sqrt(1+1e-5)

typedef __bf16 bf16x8 __attribute__((ext_vector_type(8)));
typedef float  f32x4  __attribute__((ext_vector_type(4)));

__device__ __forceinline__ void split2(float x, __bf16& hi, __bf16& lo){
    hi = (__bf16)x;
    lo = (__bf16)(x - (float)hi);
}

// ---------------- graph prep ----------------

__global__ void k_zero_int(int* __restrict__ p, int n){
    int i = blockIdx.x*256 + threadIdx.x;
    if(i < n) p[i] = 0;
}

__global__ void k_count(const int* __restrict__ dst, int* __restrict__ counts){
    int e = blockIdx.x*256 + threadIdx.x;
    if(e < E_EDGES) atomicAdd(&counts[dst[e]], 1);
}

__global__ void k_scan1(int* __restrict__ counts, int* __restrict__ bsums){
    __shared__ int s[1024];
    int t = threadIdx.x;
    int gi = blockIdx.x*1024 + t;
    int v = counts[gi];
    s[t] = v; __syncthreads();
    for(int off=1; off<1024; off<<=1){
        int x = (t>=off) ? s[t-off] : 0;
        __syncthreads();
        s[t] += x;
        __syncthreads();
    }
    counts[gi] = s[t] - v;
    if(t == 1023) bsums[blockIdx.x] = s[t];
}

__global__ void k_scan2(int* __restrict__ bsums){
    __shared__ int s[128];
    int t = threadIdx.x;
    int v = bsums[t]; s[t] = v; __syncthreads();
    for(int off=1; off<128; off<<=1){
        int x = (t>=off) ? s[t-off] : 0;
        __syncthreads();
        s[t] += x;
        __syncthreads();
    }
    bsums[t] = s[t] - v;
}

__global__ void k_scan3(const int* __restrict__ counts, const int* __restrict__ bsums,
                        int* __restrict__ rowptr){
    int i = blockIdx.x*1024 + threadIdx.x;
    rowptr[i] = counts[i] + bsums[blockIdx.x];
    if(i == 0) rowptr[N_NODES] = E_EDGES;
}

__global__ void k_dinv_cursor(const int* __restrict__ rowptr, float* __restrict__ dinv,
                              int* __restrict__ cursor){
    int n = blockIdx.x*256 + threadIdx.x;
    if(n < N_NODES){
        int a = rowptr[n], b = rowptr[n+1];
        dinv[n] = rsqrtf((float)(b - a) + 1.0f);
        cursor[n] = a;
    }
}

__global__ void k_fill(const int* __restrict__ src, const int* __restrict__ dst,
                       int* __restrict__ cursor, int* __restrict__ csr){
    int e = blockIdx.x*256 + threadIdx.x;
    if(e < E_EDGES){
        int p = atomicAdd(&cursor[dst[e]], 1);
        csr[p] = src[e];
    }
}

// ---------------- split-conversion kernels ----------------

__global__ void k_split_x(const float* __restrict__ x, __bf16* __restrict__ xh,
                          __bf16* __restrict__ xl){
    int idx = blockIdx.x*256 + threadIdx.x;          // N*32
    int n = idx >> 5, k = idx & 31;
    float v = (k < NF_DIM) ? x[n*NF_DIM + k] : 0.f;
    split2(v, xh[idx], xl[idx]);
}

__global__ void k_split_wemb(const float* __restrict__ W, __bf16* __restrict__ th,
                             __bf16* __restrict__ tl){
    int idx = blockIdx.x*256 + threadIdx.x;          // 128*32  (c-major, k padded)
    int c = idx >> 5, k = idx & 31;
    float v = (k < NF_DIM) ? W[k*H_DIM + c] : 0.f;
    split2(v, th[idx], tl[idx]);
}

__global__ void k_split_wg(const float* __restrict__ Wg, __bf16* __restrict__ th,
                           __bf16* __restrict__ tl){
    int idx = blockIdx.x*256 + threadIdx.x;          // 3*128*128
    int l = idx >> 14, i = idx & 16383;
    int k = i >> 7, c = i & 127;
    float v = Wg[idx];
    int o = (l << 14) + (c << 7) + k;                // transposed: [l][c][k]
    split2(v, th[o], tl[o]);
}

__global__ void k_split_gf(const float* __restrict__ gf, __bf16* __restrict__ ah,
                           __bf16* __restrict__ al){
    unsigned idx = blockIdx.x*256 + threadIdx.x;     // 2048*4416
    unsigned r = idx / GF_PAD, k = idx - r*GF_PAD;
    float v = (k < GF_DIM) ? gf[(size_t)r*GF_DIM + k] : 0.f;
    split2(v, ah[idx], al[idx]);
}

__global__ void k_split_wge1(const float* __restrict__ W, __bf16* __restrict__ th,
                             __bf16* __restrict__ tl){
    unsigned idx = blockIdx.x*256 + threadIdx.x;     // 256*4416 (c-major, k padded)
    unsigned c = idx / GF_PAD, k = idx - c*GF_PAD;
    float v = (k < GF_DIM) ? W[(size_t)k*256 + c] : 0.f;
    split2(v, th[idx], tl[idx]);
}

// ---------------- embedding via MFMA:  relu(x @ W_emb + b) -> (Hh,Hl) ----------------

__global__ __launch_bounds__(256)
void k_emb_mfma(const __bf16* __restrict__ xh, const __bf16* __restrict__ xl,
                const __bf16* __restrict__ wth, const __bf16* __restrict__ wtl,
                const float* __restrict__ bias, __bf16* __restrict__ Hh,
                __bf16* __restrict__ Hl){
    int wave = threadIdx.x >> 6, lane = threadIdx.x & 63;
    int lr = lane & 15, lq = lane >> 4;
    int rbase = blockIdx.x*128 + wave*32;
    const f32x4 zero4 = {0.f,0.f,0.f,0.f};
    bf16x8 A0h = *(const bf16x8*)(xh + (size_t)(rbase + lr)*32 + lq*8);
    bf16x8 A0l = *(const bf16x8*)(xl + (size_t)(rbase + lr)*32 + lq*8);
    bf16x8 A1h = *(const bf16x8*)(xh + (size_t)(rbase + 16 + lr)*32 + lq*8);
    bf16x8 A1l = *(const bf16x8*)(xl + (size_t)(rbase + 16 + lr)*32 + lq*8);
    #pragma unroll
    for(int ct=0;ct<8;ct++){
        int col = ct*16 + lr;
        bf16x8 Bh = *(const bf16x8*)(wth + col*32 + lq*8);
        bf16x8 Bl = *(const bf16x8*)(wtl + col*32 + lq*8);
        f32x4 a0 = zero4, a1 = zero4;
        a0 = __builtin_amdgcn_mfma_f32_16x16x32_bf16(A0h, Bh, a0, 0,0,0);
        a0 = __builtin_amdgcn_mfma_f32_16x16x32_bf16(A0l, Bh, a0, 0,0,0);
        a0 = __builtin_amdgcn_mfma_f32_16x16x32_bf16(A0h, Bl, a0, 0,0,0);
        a1 = __builtin_amdgcn_mfma_f32_16x16x32_bf16(A1h, Bh, a1, 0,0,0);
        a1 = __builtin_amdgcn_mfma_f32_16x16x32_bf16(A1l, Bh, a1, 0,0,0);
        a1 = __builtin_amdgcn_mfma_f32_16x16x32_bf16(A1h, Bl, a1, 0,0,0);
        float bb = bias[col];
        #pragma unroll
        for(int r=0;r<4;r++){
            size_t i0 = (size_t)(rbase + lq*4 + r)*H_DIM + col;
            size_t i1 = (size_t)(rbase + 16 + lq*4 + r)*H_DIM + col;
            float v0 = fmaxf(a0[r] + bb, 0.f);
            float v1 = fmaxf(a1[r] + bb, 0.f);
            split2(v0, Hh[i0], Hl[i0]);
            split2(v1, Hh[i1], Hl[i1]);
        }
    }
}

// ---------------- node matmul via MFMA: hw = (Hh+Hl) @ Wg ----------------

__global__ __launch_bounds__(256)
void k_mm_mfma(const __bf16* __restrict__ Ah, const __bf16* __restrict__ Al,
               const __bf16* __restrict__ Bth, const __bf16* __restrict__ Btl,
               float* __restrict__ C){
    int wave = threadIdx.x >> 6, lane = threadIdx.x & 63;
    int lr = lane & 15, lq = lane >> 4;
    int rbase = blockIdx.x*128 + wave*32;
    const f32x4 zero4 = {0.f,0.f,0.f,0.f};
    size_t o0 = (size_t)(rbase + lr)*H_DIM + lq*8;
    size_t o1 = o0 + (size_t)16*H_DIM;
    bf16x8 A0h[4], A0l[4], A1h[4], A1l[4];
    #pragma unroll
    for(int ks=0;ks<4;ks++){
        A0h[ks] = *(const bf16x8*)(Ah + o0 + ks*32);
        A0l[ks] = *(const bf16x8*)(Al + o0 + ks*32);
        A1h[ks] = *(const bf16x8*)(Ah + o1 + ks*32);
        A1l[ks] = *(const bf16x8*)(Al + o1 + ks*32);
    }
    #pragma unroll
    for(int ct=0;ct<8;ct++){
        int cb = ct*16 + lr;
        f32x4 a0 = zero4, a1 = zero4;
        #pragma unroll
        for(int ks=0;ks<4;ks++){
            bf16x8 Bh = *(const bf16x8*)(Bth + cb*H_DIM + ks*32 + lq*8);
            bf16x8 Bl = *(const bf16x8*)(Btl + cb*H_DIM + ks*32 + lq*8);
            a0 = __builtin_amdgcn_mfma_f32_16x16x32_bf16(A0h[ks], Bh, a0, 0,0,0);
            a0 = __builtin_amdgcn_mfma_f32_16x16x32_bf16(A0l[ks], Bh, a0, 0,0,0);
            a0 = __builtin_amdgcn_mfma_f32_16x16x32_bf16(A0h[ks], Bl, a0, 0,0,0);
            a1 = __builtin_amdgcn_mfma_f32_16x16x32_bf16(A1h[ks], Bh, a1, 0,0,0);
            a1 = __builtin_amdgcn_mfma_f32_16x16x32_bf16(A1l[ks], Bh, a1, 0,0,0);
            a1 = __builtin_amdgcn_mfma_f32_16x16x32_bf16(A1h[ks], Bl, a1, 0,0,0);
        }
        #pragma unroll
        for(int r=0;r<4;r++){
            C[(size_t)(rbase + lq*4 + r)*H_DIM + ct*16 + lr]      = a0[r];
            C[(size_t)(rbase + 16 + lq*4 + r)*H_DIM + ct*16 + lr] = a1[r];
        }
    }
}

// ---------------- gene GEMM via MFMA, split-K with fp32 atomics ----------------

__global__ __launch_bounds__(256)
void k_gemm_gf_mfma(const __bf16* __restrict__ Ah, const __bf16* __restrict__ Al,
                    const __bf16* __restrict__ Bth, const __bf16* __restrict__ Btl,
                    float* __restrict__ out){
    int rt = blockIdx.x & 31;       // 32 row tiles of 64
    int sp = blockIdx.x >> 5;       // 8 k-splits
    int ks0 = (sp*138) >> 3, ks1 = ((sp+1)*138) >> 3;
    int wave = threadIdx.x >> 6, lane = threadIdx.x & 63;
    int lr = lane & 15, lq = lane >> 4;
    int rbase = rt*64 + (wave & 1)*32;
    int cbase = (wave >> 1)*128;
    const f32x4 zero4 = {0.f,0.f,0.f,0.f};
    f32x4 acc[8][2];
    #pragma unroll
    for(int ct=0;ct<8;ct++){ acc[ct][0] = zero4; acc[ct][1] = zero4; }
    for(int ks=ks0; ks<ks1; ks++){
        int kc = ks*32;
        size_t oa0 = (size_t)(rbase + lr)*GF_PAD + kc + lq*8;
        size_t oa1 = oa0 + (size_t)16*GF_PAD;
        bf16x8 A0h = *(const bf16x8*)(Ah + oa0);
        bf16x8 A0l = *(const bf16x8*)(Al + oa0);
        bf16x8 A1h = *(const bf16x8*)(Ah + oa1);
        bf16x8 A1l = *(const bf16x8*)(Al + oa1);
        #pragma unroll
        for(int ct=0;ct<8;ct++){
            size_t bo = (size_t)(cbase + ct*16 + lr)*GF_PAD + kc + lq*8;
            bf16x8 Bh = *(const bf16x8*)(Bth + bo);
            bf16x8 Bl = *(const bf16x8*)(Btl + bo);
            acc[ct][0] = __builtin_amdgcn_mfma_f32_16x16x32_bf16(A0h, Bh, acc[ct][0], 0,0,0);
            acc[ct][0] = __builtin_amdgcn_mfma_f32_16x16x32_bf16(A0l, Bh, acc[ct][0], 0,0,0);
            acc[ct][0] = __builtin_amdgcn_mfma_f32_16x16x32_bf16(A0h, Bl, acc[ct][0], 0,0,0);
            acc[ct][1] = __builtin_amdgcn_mfma_f32_16x16x32_bf16(A1h, Bh, acc[ct][1], 0,0,0);
            acc[ct][1] = __builtin_amdgcn_mfma_f32_16x16x32_bf16(A1l, Bh, acc[ct][1], 0,0,0);
            acc[ct][1] = __builtin_amdgcn_mfma_f32_16x16x32_bf16(A1h, Bl, acc[ct][1], 0,0,0);
        }
    }
    #pragma unroll
    for(int ct=0;ct<8;ct++)
        #pragma unroll
        for(int s=0;s<2;s++)
            #pragma unroll
            for(int r=0;r<4;r++)
                atomicAdd(&out[(size_t)(rbase + s*16 + lq*4 + r)*256 + cbase + ct*16 + lr],
                          acc[ct][s][r]);
}

// ---------------- GCN aggregate + bias + BN + ReLU + residual -> (Hh,Hl) ----------------

__global__ void k_aggregate(const float* __restrict__ hw, const float* __restrict__ dinv,
                            const int* __restrict__ rowptr, const int* __restrict__ csr,
                            const float* __restrict__ bias, const float* __restrict__ gamma,
                            const float* __restrict__ beta, __bf16* __restrict__ Hh,
                            __bf16* __restrict__ Hl, int residual){
    int wave = threadIdx.x >> 6, lane = threadIdx.x & 63;
    int n = blockIdx.x*4 + wave;
    int c = lane*2;
    float dn = dinv[n];
    const float2* hw2 = (const float2*)hw;
    float2 self = hw2[n*64 + lane];
    float ax = self.x*dn, ay = self.y*dn;
    int j0 = rowptr[n], j1 = rowptr[n+1];
    for(int j=j0;j<j1;j++){
        int s = csr[j];
        float ds = dinv[s];
        float2 v = hw2[s*64 + lane];
        ax = fmaf(v.x, ds, ax);
        ay = fmaf(v.y, ds, ay);
    }
    float v0 = fmaf(ax, dn, bias[c]);
    float v1 = fmaf(ay, dn, bias[c+1]);
    v0 = fmaf(v0, gamma[c]*BN_SCALE,   beta[c]);
    v1 = fmaf(v1, gamma[c+1]*BN_SCALE, beta[c+1]);
    v0 = fmaxf(v0, 0.f); v1 = fmaxf(v1, 0.f);
    size_t i0 = (size_t)n*H_DIM + c;
    if(residual){
        v0 += (float)Hh[i0]   + (float)Hl[i0];
        v1 += (float)Hh[i0+1] + (float)Hl[i0+1];
    }
    split2(v0, Hh[i0],   Hl[i0]);
    split2(v1, Hh[i0+1], Hl[i0+1]);
}

// ---------------- pooling ----------------

__global__ void k_pool(const __bf16* __restrict__ Hh, const __bf16* __restrict__ Hl,
                       float* __restrict__ pool){
    int g = blockIdx.x, c = threadIdx.x;   // 128 threads
    const __bf16* bh = Hh + (size_t)g*64*H_DIM;
    const __bf16* bl = Hl + (size_t)g*64*H_DIM;
    float s = 0.f, m = -3.4e38f;
    for(int i=0;i<64;i++){
        float v = (float)bh[i*H_DIM + c] + (float)bl[i*H_DIM + c];
        s += v; m = fmaxf(m, v);
    }
    pool[g*256 + c]       = s * (1.f/64.f);
    pool[g*256 + 128 + c] = m;
}

// ---------------- gene branch epilogue helpers ----------------

__global__ void k_ginit(const float* __restrict__ bias, float* __restrict__ out){
    int i = blockIdx.x*256 + threadIdx.x;   // B*256
    out[i] = bias[i & 255];
}

__global__ void k_bnrelu256(float* __restrict__ g1, const float* __restrict__ gamma,
                            const float* __restrict__ beta){
    int i = blockIdx.x*256 + threadIdx.x;
    int c = i & 255;
    float v = fmaf(g1[i], gamma[c]*BN_SCALE, beta[c]);
    g1[i] = fmaxf(v, 0.f);
}

// ---------------- small dense layers ----------------

__global__ void k_dense(const float* __restrict__ A, int ldA, const float* __restrict__ W,
                        const float* __restrict__ bias, const float* __restrict__ gamma,
                        const float* __restrict__ beta, float* __restrict__ out, int ldOut,
                        int K, int logK, int NC, int relu){
    extern __shared__ float sA[];
    int rowBase = blockIdx.x*16;
    int c = threadIdx.x;
    for(int idx=threadIdx.x; idx<16*K; idx+=NC){
        int r = idx >> logK, k = idx & (K-1);
        sA[idx] = A[(rowBase+r)*ldA + k];
    }
    __syncthreads();
    float acc[16];
    float bb = bias[c];
    #pragma unroll
    for(int r=0;r<16;r++) acc[r] = bb;
    for(int k=0;k<K;k++){
        float w = W[k*NC + c];
        #pragma unroll
        for(int r=0;r<16;r++) acc[r] = fmaf(sA[(r<<logK)+k], w, acc[r]);
    }
    float gsc = 1.f, bsh = 0.f;
    if(gamma){ gsc = gamma[c]*BN_SCALE; bsh = beta[c]; }
    #pragma unroll
    for(int r=0;r<16;r++){
        float v = acc[r];
        if(gamma) v = fmaf(v, gsc, bsh);
        if(relu)  v = fmaxf(v, 0.f);
        out[(rowBase+r)*ldOut + c] = v;
    }
}

__global__ void k_final(const float* __restrict__ z2, const float* __restrict__ Wh3,
                        const float* __restrict__ bh3, float* __restrict__ out){
    int r = blockIdx.x*256 + threadIdx.x;
    if(r < B_GR){
        float acc = bh3[0];
        #pragma unroll
        for(int k=0;k<64;k++) acc = fmaf(z2[r*64+k], Wh3[k], acc);
        out[r] = acc;
    }
}

// ---------------- launch ----------------

extern "C" void kernel_launch(void* const* d_in, const int* in_sizes, int n_in,
                              void* d_out, int out_size, void* d_ws, size_t ws_size,
                              hipStream_t stream){
    (void)in_sizes; (void)n_in; (void)out_size; (void)ws_size;
    const float* x    = (const float*)d_in[0];
    const float* gf   = (const float*)d_in[1];
    const int*   ei   = (const int*)  d_in[2];
    const float* W_emb= (const float*)d_in[4];
    const float* b_emb= (const float*)d_in[5];
    const float* Wg   = (const float*)d_in[6];
    const float* bg   = (const float*)d_in[7];
    const float* bn_g = (const float*)d_in[8];
    const float* bn_b = (const float*)d_in[9];
    const float* Wd1  = (const float*)d_in[10];
    const float* bd1  = (const float*)d_in[11];
    const float* Wd2  = (const float*)d_in[12];
    const float* bd2  = (const float*)d_in[13];
    const float* Wge1 = (const float*)d_in[14];
    const float* bge1 = (const float*)d_in[15];
    const float* g_g  = (const float*)d_in[16];
    const float* g_b  = (const float*)d_in[17];
    const float* Wge2 = (const float*)d_in[18];
    const float* bge2 = (const float*)d_in[19];
    const float* Wh1  = (const float*)d_in[20];
    const float* bh1  = (const float*)d_in[21];
    const float* h_g  = (const float*)d_in[22];
    const float* h_b  = (const float*)d_in[23];
    const float* Wh2  = (const float*)d_in[24];
    const float* bh2  = (const float*)d_in[25];
    const float* Wh3  = (const float*)d_in[26];
    const float* bh3  = (const float*)d_in[27];
    float* outp = (float*)d_out;

    char* base = (char*)d_ws;
    __bf16* Hh = (__bf16*)base;                         // 32 MiB
    __bf16* Hl = (__bf16*)(base + 33554432);            // 32 MiB
    char*   R  = base + 67108864;                       // 64 MiB multi-use region
    float*  hw = (float*)R;                             // N*128 fp32 (layers)
    __bf16* gfh = (__bf16*)R;                           // 2048*4416 bf16
    __bf16* gfl = (__bf16*)(R + 18087936);
    __bf16* wge_th = (__bf16*)(R + 36175872);           // 256*4416 bf16
    __bf16* wge_tl = (__bf16*)(R + 38436864);
    __bf16* xsh = (__bf16*)R;                           // N*32 bf16 (emb phase)
    __bf16* xsl = (__bf16*)(R + 8388608);
    float* pool = (float*)(base + 134217728);           // 2048*256
    float* g1   = pool + B_GR*256;                      // 2048*256
    float* t1   = g1   + B_GR*256;                      // 2048*128 (also hosts Wt splits early)
    float* comb = t1   + B_GR*128;                      // 2048*256
    float* z    = comb + B_GR*256;                      // 2048*128
    float* z2   = z    + B_GR*128;                      // 2048*64
    int* rowptr = (int*)(z2 + B_GR*64);
    int* cursor = rowptr + (N_NODES+1);
    int* csr    = cursor + N_NODES;
    int* bsums  = csr + E_EDGES;
    // weight-split scratch inside t1 (t1 written only after GCN layers finish)
    __bf16* wg_th = (__bf16*)t1;                        // 3*16384
    __bf16* wg_tl = wg_th + 3*16384;
    __bf16* we_th = wg_tl + 3*16384;                    // 128*32
    __bf16* we_tl = we_th + 128*32;

    const int* src = ei;
    const int* dst = ei + E_EDGES;

    // graph prep
    k_zero_int   <<<N_NODES/256, 256, 0, stream>>>(cursor, N_NODES);
    k_count      <<<E_EDGES/256, 256, 0, stream>>>(dst, cursor);
    k_scan1      <<<128, 1024, 0, stream>>>(cursor, bsums);
    k_scan2      <<<1, 128, 0, stream>>>(bsums);
    k_scan3      <<<128, 1024, 0, stream>>>(cursor, bsums, rowptr);
    k_dinv_cursor<<<N_NODES/256, 256, 0, stream>>>(rowptr, (float*)(base + 134217728 - 4*N_NODES), cursor); // placeholder overwritten below
    // NOTE: dinv storage — reuse tail of R region is unsafe; use dedicated slot:
    // (we instead place dinv right after bsums)
    // re-run with proper pointer:
    {
        int* endi = bsums + 128;
        float* dinv = (float*)endi;
        k_dinv_cursor<<<N_NODES/256, 256, 0, stream>>>(rowptr, dinv, cursor);
        k_fill       <<<E_EDGES/256, 256, 0, stream>>>(src, dst, cursor, csr);

        // gene branch first (uses R for gf splits)
        k_split_gf   <<<(B_GR*GF_PAD)/256, 256, 0, stream>>>(gf, gfh, gfl);
        k_split_wge1 <<<(256*GF_PAD)/256, 256, 0, stream>>>(Wge1, wge_th, wge_tl);
        k_ginit      <<<(B_GR*256)/256, 256, 0, stream>>>(bge1, g1);
        k_gemm_gf_mfma<<<256, 256, 0, stream>>>(gfh, gfl, wge_th, wge_tl, g1);
        k_bnrelu256  <<<(B_GR*256)/256, 256, 0, stream>>>(g1, g_g, g_b);

        // embedding (R reused for x splits)
        k_split_x    <<<(N_NODES*32)/256, 256, 0, stream>>>(x, xsh, xsl);
        k_split_wemb <<<(128*32)/256, 256, 0, stream>>>(W_emb, we_th, we_tl);
        k_split_wg   <<<(3*16384)/256, 256, 0, stream>>>(Wg, wg_th, wg_tl);
        k_emb_mfma   <<<N_NODES/128, 256, 0, stream>>>(xsh, xsl, we_th, we_tl, b_emb, Hh, Hl);

        // 3 GCN layers (R reused as hw)
        for(int i=0;i<3;i++){
            k_mm_mfma  <<<N_NODES/128, 256, 0, stream>>>(Hh, Hl, wg_th + i*16384, wg_tl + i*16384, hw);
            k_aggregate<<<N_NODES/4, 256, 0, stream>>>(hw, dinv, rowptr, csr,
                                                       bg + i*H_DIM, bn_g + i*H_DIM,
                                                       bn_b + i*H_DIM, Hh, Hl, i > 0);
        }

        // pooling + heads
        k_pool<<<B_GR, 128, 0, stream>>>(Hh, Hl, pool);
        k_dense<<<B_GR/16, 128, 16*256*4, stream>>>(pool, 256, Wd1, bd1, nullptr, nullptr, t1,   128, 256, 8, 128, 1);
        k_dense<<<B_GR/16, 128, 16*128*4, stream>>>(t1,   128, Wd2, bd2, nullptr, nullptr, comb, 256, 128, 7, 128, 0);
        k_dense<<<B_GR/16, 128, 16*256*4, stream>>>(g1,   256, Wge2, bge2, nullptr, nullptr, comb+128, 256, 256, 8, 128, 1);
        k_dense<<<B_GR/16, 128, 16*256*4, stream>>>(comb, 256, Wh1, bh1, h_g, h_b, z, 128, 256, 8, 128, 1);
        k_dense<<<B_GR/16, 64,  16*128*4, stream>>>(z,    128, Wh2, bh2, nullptr, nullptr, z2, 64, 128, 7, 64, 1);
        k_final<<<B_GR/256, 256, 0, stream>>>(z2, Wh3, bh3, outp);
    }
}